// Round 7
// baseline (367.170 us; speedup 1.0000x reference)
//
#include <hip/hip_runtime.h>
#include <hip/hip_bf16.h>
#include <math.h>
#include <float.h>

// dims
constexpr int NQ = 64, NK = 256, SSZ = 64, D = 512, FF = 2048;
constexpr int PAIRS = NQ * NK;          // 16384
constexpr int ROWSX = 2 * PAIRS;        // 32768
constexpr int NX = (NQ + NK) * SSZ;     // 20480 rows of X = [tgt;mem]

typedef __bf16 bf16x8 __attribute__((ext_vector_type(8)));
typedef float floatx16 __attribute__((ext_vector_type(16)));

// ---------------- K0: sigmoid of score_embed (or 1.0 if !flag) -------------
__global__ void k_sig(const float* __restrict__ se, const int* __restrict__ flag,
                      float* __restrict__ sig) {
    int i = blockIdx.x * blockDim.x + threadIdx.x;
    if (i < SSZ * SSZ) {
        sig[i] = (*flag) ? 1.0f / (1.0f + expf(-se[i])) : 1.0f;
    }
}

// ---------------- K0b: convert X=[tgt;mem], W1, W2 to bf16 -----------------
__global__ __launch_bounds__(256) void k_cvt(
        const float* __restrict__ tgt, const float* __restrict__ mem,
        const float* __restrict__ W1, const float* __restrict__ W2,
        __hip_bfloat16* __restrict__ Xb, __hip_bfloat16* __restrict__ W1b,
        __hip_bfloat16* __restrict__ W2b) {
    constexpr int T4 = NQ * SSZ * D / 4;   // tgt float4 count
    constexpr int X4 = NX * D / 4;         // X float4 count
    constexpr int W4 = D * D / 4;          // W1 float4 count
    constexpr int V4 = FF * 64 / 4;        // W2 float4 count
    int idx = blockIdx.x * 256 + threadIdx.x;
    if (idx >= X4 + W4 + V4) return;
    const float* src;
    __hip_bfloat16* dst;
    if (idx < T4)           { src = tgt + (size_t)idx * 4;             dst = Xb + (size_t)idx * 4; }
    else if (idx < X4)      { src = mem + (size_t)(idx - T4) * 4;      dst = Xb + (size_t)idx * 4; }
    else if (idx < X4 + W4) { src = W1 + (size_t)(idx - X4) * 4;       dst = W1b + (size_t)(idx - X4) * 4; }
    else                    { src = W2 + (size_t)(idx - X4 - W4) * 4;  dst = W2b + (size_t)(idx - X4 - W4) * 4; }
    float4 v = *reinterpret_cast<const float4*>(src);
    union { __hip_bfloat16 h[4]; uint2 u; } o;
    o.h[0] = __float2bfloat16(v.x); o.h[1] = __float2bfloat16(v.y);
    o.h[2] = __float2bfloat16(v.z); o.h[3] = __float2bfloat16(v.w);
    *reinterpret_cast<uint2*>(dst) = o.u;
}

// ---------------- K1: MFMA GEMM1: C = Xb @ W1b^T + b1 (bf16 out) -----------
// 128x128 tile, LDR=72 padded LDS (144 B row stride -> conflict-free).
__global__ __launch_bounds__(256, 3) void k_gemm1_mfma(
        const __hip_bfloat16* __restrict__ Xb, const __hip_bfloat16* __restrict__ W1b,
        const float* __restrict__ b1, const int* __restrict__ flag,
        __hip_bfloat16* __restrict__ C) {
    constexpr int LDR = 72;
    __shared__ __attribute__((aligned(16))) unsigned short lds[2 * 128 * LDR]; // 36864 B
    unsigned short* As = lds;
    unsigned short* Bs = lds + 128 * LDR;
    const unsigned short* Xu = reinterpret_cast<const unsigned short*>(Xb);
    const unsigned short* Wu = reinterpret_cast<const unsigned short*>(W1b);
    unsigned short* Cu = reinterpret_cast<unsigned short*>(C);

    int tid = threadIdx.x;
    int bm = blockIdx.x >> 2, bn = blockIdx.x & 3;
    int m0 = bm * 128, n0 = bn * 128;

    if (!(*flag)) {
#pragma unroll
        for (int i = 0; i < 8; ++i) {
            int id = i * 256 + tid;
            int row = id >> 4, ch = id & 15;
            uint4 v = *reinterpret_cast<const uint4*>(Xu + (size_t)(m0 + row) * D + n0 + ch * 8);
            *reinterpret_cast<uint4*>(Cu + (size_t)(m0 + row) * D + n0 + ch * 8) = v;
        }
        return;
    }

    int w = tid >> 6, l = tid & 63, h = l >> 5, c = l & 31;
    int wm = w >> 1, wn = w & 1;
    floatx16 acc00 = {}, acc01 = {}, acc10 = {}, acc11 = {};

    for (int kb = 0; kb < D; kb += 64) {
#pragma unroll
        for (int i = 0; i < 4; ++i) {
            int id = i * 256 + tid;
            int row = id >> 3, c8 = id & 7;
            uint4 va = *reinterpret_cast<const uint4*>(Xu + (size_t)(m0 + row) * D + kb + c8 * 8);
            *reinterpret_cast<uint4*>(&As[row * LDR + c8 * 8]) = va;
            uint4 vb = *reinterpret_cast<const uint4*>(Wu + (size_t)(n0 + row) * D + kb + c8 * 8);
            *reinterpret_cast<uint4*>(&Bs[row * LDR + c8 * 8]) = vb;
        }
        __syncthreads();
        const unsigned short* pA = As + (wm * 64) * LDR;
        const unsigned short* pB = Bs + (wn * 64) * LDR;
#pragma unroll
        for (int st = 0; st < 4; ++st) {
            int d = st * 16 + h * 8;
            bf16x8 a0 = *reinterpret_cast<const bf16x8*>(pA + c * LDR + d);
            bf16x8 a1 = *reinterpret_cast<const bf16x8*>(pA + (32 + c) * LDR + d);
            bf16x8 b0 = *reinterpret_cast<const bf16x8*>(pB + c * LDR + d);
            bf16x8 b1 = *reinterpret_cast<const bf16x8*>(pB + (32 + c) * LDR + d);
            acc00 = __builtin_amdgcn_mfma_f32_32x32x16_bf16(a0, b0, acc00, 0, 0, 0);
            acc01 = __builtin_amdgcn_mfma_f32_32x32x16_bf16(a0, b1, acc01, 0, 0, 0);
            acc10 = __builtin_amdgcn_mfma_f32_32x32x16_bf16(a1, b0, acc10, 0, 0, 0);
            acc11 = __builtin_amdgcn_mfma_f32_32x32x16_bf16(a1, b1, acc11, 0, 0, 0);
        }
        __syncthreads();
    }

    int mbase = m0 + wm * 64, nbase = n0 + wn * 64;
    float bia0 = b1[nbase + c], bia1 = b1[nbase + 32 + c];
#pragma unroll
    for (int mi = 0; mi < 2; ++mi) {
        const floatx16& A0 = mi ? acc10 : acc00;
        const floatx16& A1 = mi ? acc11 : acc01;
#pragma unroll
        for (int r = 0; r < 16; ++r) {
            int m = mbase + mi * 32 + (r & 3) + 8 * (r >> 2) + 4 * h;
            C[(size_t)m * D + nbase + c] = __float2bfloat16(A0[r] + bia0);
            C[(size_t)m * D + nbase + 32 + c] = __float2bfloat16(A1[r] + bia1);
        }
    }
}

// ---------------- K2: MFMA score as flattened 128x128 GEMM + dual max ------
// Flattened GEMM: rows = (ki,s) [16384], cols = (qi,t) [4096], K = 512.
// Block (bkk, bqq): A = K-rows bkk*128.., B = Q-rows bqq*128.. (2 tiles only).
// Wave (wm, wn)'s 64x64 quadrant == complete pair (ki = bkk*2+wm, qi = bqq*2+wn).
__global__ __launch_bounds__(256, 4) void k_score_mfma(
        const __hip_bfloat16* __restrict__ QKb, const float* __restrict__ sig,
        float* __restrict__ xbuf) {
    constexpr int LDR = 72;
    __shared__ __attribute__((aligned(16))) unsigned short lds[2 * 128 * LDR]; // 36864 B
    unsigned short* As = lds;                 // K rows (s)
    unsigned short* Bs = lds + 128 * LDR;     // Q rows (t)
    const unsigned short* QKu = reinterpret_cast<const unsigned short*>(QKb);

    int tid = threadIdx.x;
    int w = tid >> 6, l = tid & 63, h = l >> 5, c = l & 31;
    int wm = w >> 1, wn = w & 1;
    int bkk = blockIdx.x >> 5;     // 0..127
    int bqq = blockIdx.x & 31;     // 0..31

    floatx16 acc00 = {}, acc01 = {}, acc10 = {}, acc11 = {};

    for (int kb = 0; kb < D; kb += 64) {
#pragma unroll
        for (int i = 0; i < 4; ++i) {
            int id = i * 256 + tid;
            int row = id >> 3, c8 = id & 7;
            uint4 va = *reinterpret_cast<const uint4*>(
                QKu + (size_t)(NQ * SSZ + bkk * 128 + row) * D + kb + c8 * 8);
            *reinterpret_cast<uint4*>(&As[row * LDR + c8 * 8]) = va;
            uint4 vb = *reinterpret_cast<const uint4*>(
                QKu + (size_t)(bqq * 128 + row) * D + kb + c8 * 8);
            *reinterpret_cast<uint4*>(&Bs[row * LDR + c8 * 8]) = vb;
        }
        __syncthreads();
        const unsigned short* pA = As + (wm * 64) * LDR;
        const unsigned short* pB = Bs + (wn * 64) * LDR;
#pragma unroll
        for (int st = 0; st < 4; ++st) {
            int d = st * 16 + h * 8;
            bf16x8 a0 = *reinterpret_cast<const bf16x8*>(pA + c * LDR + d);
            bf16x8 a1 = *reinterpret_cast<const bf16x8*>(pA + (32 + c) * LDR + d);
            bf16x8 b0 = *reinterpret_cast<const bf16x8*>(pB + c * LDR + d);
            bf16x8 b1 = *reinterpret_cast<const bf16x8*>(pB + (32 + c) * LDR + d);
            acc00 = __builtin_amdgcn_mfma_f32_32x32x16_bf16(a0, b0, acc00, 0, 0, 0);
            acc01 = __builtin_amdgcn_mfma_f32_32x32x16_bf16(a0, b1, acc01, 0, 0, 0);
            acc10 = __builtin_amdgcn_mfma_f32_32x32x16_bf16(a1, b0, acc10, 0, 0, 0);
            acc11 = __builtin_amdgcn_mfma_f32_32x32x16_bf16(a1, b1, acc11, 0, 0, 0);
        }
        __syncthreads();
    }

    // stage sig (16 KB) over the tile LDS
    float* sigl = reinterpret_cast<float*>(lds);
#pragma unroll
    for (int i = 0; i < 4; ++i) {
        int idx = i * 256 + tid;
        *reinterpret_cast<float4*>(sigl + idx * 4) =
            *reinterpret_cast<const float4*>(sig + idx * 4);
    }
    __syncthreads();

    // epilogue: this wave's 64x64 quadrant is pair (qi, ki)
    int qi = bqq * 2 + wn, ki = bkk * 2 + wm;
    int p = qi * 256 + ki;
    float tmax0 = -FLT_MAX, tmax1 = -FLT_MAX;
    float smax[2][16];
#pragma unroll
    for (int si = 0; si < 2; ++si) {
        const floatx16& A0 = si ? acc10 : acc00;   // t half 0
        const floatx16& A1 = si ? acc11 : acc01;   // t half 1
#pragma unroll
        for (int r = 0; r < 16; ++r) {
            int srow = si * 32 + (r & 3) + 8 * (r >> 2) + 4 * h;
            float v0 = A0[r] * sigl[srow * 64 + c];
            float v1 = A1[r] * sigl[srow * 64 + 32 + c];
            tmax0 = fmaxf(tmax0, v0);
            tmax1 = fmaxf(tmax1, v1);
            smax[si][r] = fmaxf(v0, v1);
        }
    }
    tmax0 = fmaxf(tmax0, __shfl_xor(tmax0, 32, 64));
    tmax1 = fmaxf(tmax1, __shfl_xor(tmax1, 32, 64));
    if (h == 0) {
        xbuf[(size_t)(2 * p) * 64 + c] = tmax0;
        xbuf[(size_t)(2 * p) * 64 + 32 + c] = tmax1;
    }
#pragma unroll
    for (int stage = 1; stage < 32; stage <<= 1) {
#pragma unroll
        for (int si = 0; si < 2; ++si)
#pragma unroll
            for (int r = 0; r < 16; ++r)
                smax[si][r] = fmaxf(smax[si][r], __shfl_xor(smax[si][r], stage, 64));
    }
    if (c == 0) {
#pragma unroll
        for (int si = 0; si < 2; ++si)
#pragma unroll
            for (int r = 0; r < 16; ++r) {
                int srow = si * 32 + (r & 3) + 8 * (r >> 2) + 4 * h;
                xbuf[(size_t)(2 * p + 1) * 64 + srow] = smax[si][r];
            }
    }
}

// ---------------- K3: row stats S1[64], S2[64][64] over xbuf ---------------
__global__ __launch_bounds__(256) void k_stats1(const float* __restrict__ xbuf,
        double* __restrict__ S1d, double* __restrict__ S2d) {
    __shared__ float xr[8][64];
    int tid = threadIdx.x;
    int row0 = blockIdx.x * 256;
    float acc[16] = {};
    float s1 = 0.f;
    int pbase = tid * 16;
    int tr = tid >> 6, tc = tid & 63;
    for (int it = 0; it < 32; ++it) {
        int r = row0 + it * 8;
        xr[tr][tc] = xbuf[(size_t)(r + tr) * 64 + tc];
        xr[4 + tr][tc] = xbuf[(size_t)(r + 4 + tr) * 64 + tc];
        __syncthreads();
#pragma unroll
        for (int e = 0; e < 16; ++e) {
            int a = (pbase + e) >> 6, b = (pbase + e) & 63;
            float t = 0.f;
#pragma unroll
            for (int k = 0; k < 8; ++k) t += xr[k][a] * xr[k][b];
            acc[e] += t;
        }
        if (tid < 64) {
            float t = 0.f;
#pragma unroll
            for (int k = 0; k < 8; ++k) t += xr[k][tid];
            s1 += t;
        }
        __syncthreads();
    }
#pragma unroll
    for (int e = 0; e < 16; ++e) atomicAdd(&S2d[pbase + e], (double)acc[e]);
    if (tid < 64) atomicAdd(&S1d[tid], (double)s1);
}

// ---------------- K4: finalize BN1 + normalized mean/cov -------------------
__global__ __launch_bounds__(256) void k_fin1(
        const double* __restrict__ S1d, const double* __restrict__ S2d,
        const float* __restrict__ g1, const float* __restrict__ be1,
        float* __restrict__ bn1, float* __restrict__ xbarn, float* __restrict__ covn) {
    int tid = threadIdx.x;
    double sum = 0.0, sumsq = 0.0;
    for (int j = 0; j < 64; ++j) { sum += S1d[j]; sumsq += S2d[j * 64 + j]; }
    const double Nall = (double)ROWSX * 64.0;
    double m1 = sum / Nall;
    double var1 = sumsq / Nall - m1 * m1;
    double scaled = (double)g1[0] / sqrt(var1 + 1e-5);
    if (tid == 0) { bn1[0] = (float)m1; bn1[1] = (float)scaled; }
    const double Rinv = 1.0 / (double)ROWSX;
    if (tid < 64) xbarn[tid] = (float)((S1d[tid] * Rinv - m1) * scaled) + be1[0];
#pragma unroll
    for (int e = 0; e < 16; ++e) {
        int idx = tid * 16 + e;
        int a = idx >> 6, b = idx & 63;
        double cov = S2d[idx] * Rinv - (S1d[a] * Rinv) * (S1d[b] * Rinv);
        covn[idx] = (float)(cov * scaled * scaled);
    }
}

// ---------------- K5: analytic BN2 constants per feature -------------------
__global__ __launch_bounds__(64) void k_bn2(
        const float* __restrict__ covn, const float* __restrict__ xbarn,
        const __hip_bfloat16* __restrict__ W2b,
        const float* __restrict__ g2, const float* __restrict__ be2,
        float* __restrict__ alpha, float* __restrict__ beta) {
    int f = blockIdx.x;
    int j = threadIdx.x;
    float wj = __bfloat162float(W2b[(size_t)f * 64 + j]);
    float t1 = 0.f;
    for (int b = 0; b < 64; ++b)
        t1 += covn[j * 64 + b] * __bfloat162float(W2b[(size_t)f * 64 + b]);
    float vc = wj * t1;
    float mc = wj * xbarn[j];
#pragma unroll
    for (int off = 32; off; off >>= 1) {
        vc += __shfl_down(vc, off);
        mc += __shfl_down(mc, off);
    }
    if (j == 0) {
        float t2 = g2[f] * rsqrtf(vc + 1e-5f);
        alpha[f] = t2;
        beta[f] = -t2 * mc + be2[f];
    }
}

// ---------------- K6: MFMA MLP: u = bf16(x_n) @ W2b^T, z = sum relu(a*u+b)*w3
__global__ __launch_bounds__(256, 2) void k_mlp_mfma(
        const float* __restrict__ xbuf, const float* __restrict__ bn1,
        const float* __restrict__ be1, const __hip_bfloat16* __restrict__ W2b,
        const float* __restrict__ alpha, const float* __restrict__ beta,
        const float* __restrict__ W3, const float* __restrict__ b3,
        float* __restrict__ z) {
    constexpr int LDR = 72;
    __shared__ __attribute__((aligned(16))) unsigned short Xs[128 * LDR];
    __shared__ __attribute__((aligned(16))) unsigned short Ws[128 * LDR];
    __shared__ float abw[3 * 128];
    const unsigned short* W2u = reinterpret_cast<const unsigned short*>(W2b);
    int tid = threadIdx.x;
    int w = tid >> 6, l = tid & 63, h = l >> 5, c = l & 31;
    int r0 = blockIdx.x * 128;
    float m1 = bn1[0], sc = bn1[1], sh = be1[0];

#pragma unroll
    for (int i = 0; i < 4; ++i) {
        int id = i * 256 + tid;
        int row = id >> 3, cg = id & 7;
        const float* src = xbuf + (size_t)(r0 + row) * 64 + cg * 8;
        float4 v0 = *reinterpret_cast<const float4*>(src);
        float4 v1 = *reinterpret_cast<const float4*>(src + 4);
        union { __hip_bfloat16 hh[8]; uint4 u; } o;
        o.hh[0] = __float2bfloat16((v0.x - m1) * sc + sh);
        o.hh[1] = __float2bfloat16((v0.y - m1) * sc + sh);
        o.hh[2] = __float2bfloat16((v0.z - m1) * sc + sh);
        o.hh[3] = __float2bfloat16((v0.w - m1) * sc + sh);
        o.hh[4] = __float2bfloat16((v1.x - m1) * sc + sh);
        o.hh[5] = __float2bfloat16((v1.y - m1) * sc + sh);
        o.hh[6] = __float2bfloat16((v1.z - m1) * sc + sh);
        o.hh[7] = __float2bfloat16((v1.w - m1) * sc + sh);
        *reinterpret_cast<uint4*>(&Xs[row * LDR + cg * 8]) = o.u;
    }

    float zacc[16] = {};
    for (int fc = 0; fc < FF / 128; ++fc) {
#pragma unroll
        for (int i = 0; i < 4; ++i) {
            int id = i * 256 + tid;
            int row = id >> 3, cg = id & 7;
            uint4 v = *reinterpret_cast<const uint4*>(W2u + (size_t)(fc * 128 + row) * 64 + cg * 8);
            *reinterpret_cast<uint4*>(&Ws[row * LDR + cg * 8]) = v;
        }
        if (tid < 128) {
            int f = fc * 128 + tid;
            abw[tid] = alpha[f];
            abw[128 + tid] = beta[f];
            abw[256 + tid] = W3[f];
        }
        __syncthreads();
        bf16x8 a[4];
#pragma unroll
        for (int st = 0; st < 4; ++st)
            a[st] = *reinterpret_cast<const bf16x8*>(&Xs[(w * 32 + c) * LDR + st * 16 + h * 8]);
#pragma unroll
        for (int nq = 0; nq < 4; ++nq) {
            floatx16 u = {};
#pragma unroll
            for (int st = 0; st < 4; ++st) {
                bf16x8 b = *reinterpret_cast<const bf16x8*>(&Ws[(nq * 32 + c) * LDR + st * 16 + h * 8]);
                u = __builtin_amdgcn_mfma_f32_32x32x16_bf16(a[st], b, u, 0, 0, 0);
            }
            float al = abw[nq * 32 + c];
            float bt = abw[128 + nq * 32 + c];
            float w3 = abw[256 + nq * 32 + c];
#pragma unroll
            for (int r = 0; r < 16; ++r)
                zacc[r] += fmaxf(al * u[r] + bt, 0.f) * w3;
        }
        __syncthreads();
    }
#pragma unroll
    for (int stage = 1; stage < 32; stage <<= 1)
#pragma unroll
        for (int r = 0; r < 16; ++r)
            zacc[r] += __shfl_xor(zacc[r], stage, 64);
    if (c == 0) {
        float bb = b3[0];
#pragma unroll
        for (int r = 0; r < 16; ++r) {
            int row = r0 + w * 32 + (r & 3) + 8 * (r >> 2) + 4 * h;
            z[row] = zacc[r] + bb;
        }
    }
}

// ---------------- K7: pair-sum + BN3 stats ---------------------------------
__global__ __launch_bounds__(256) void k_pair(const float* __restrict__ z,
        float* __restrict__ v, double* __restrict__ sums3) {
    int i = blockIdx.x * 256 + threadIdx.x;
    float val = z[2 * i] + z[2 * i + 1];
    v[i] = val;
    float s = val, ss = val * val;
#pragma unroll
    for (int off = 32; off; off >>= 1) {
        s += __shfl_down(s, off);
        ss += __shfl_down(ss, off);
    }
    __shared__ float bs[4], bss[4];
    int lane = threadIdx.x & 63, w = threadIdx.x >> 6;
    if (lane == 0) { bs[w] = s; bss[w] = ss; }
    __syncthreads();
    if (threadIdx.x == 0) {
        atomicAdd(&sums3[0], (double)(bs[0] + bs[1] + bs[2] + bs[3]));
        atomicAdd(&sums3[1], (double)(bss[0] + bss[1] + bss[2] + bss[3]));
    }
}

// ---------------- K8: finalize BN3 -----------------------------------------
__global__ void k_fin3(const double* __restrict__ sums3, const float* __restrict__ g3,
                       float* __restrict__ bn3) {
    double m = sums3[0] / (double)PAIRS;
    double var = sums3[1] / (double)PAIRS - m * m;
    bn3[0] = (float)m;
    bn3[1] = (float)((double)g3[0] / sqrt(var + 1e-5));
}

// ---------------- K9: write output -----------------------------------------
__global__ void k_out(const float* __restrict__ v, const float* __restrict__ bn3,
                      const float* __restrict__ be3, float* __restrict__ out) {
    int i = blockIdx.x * 256 + threadIdx.x;
    if (i < PAIRS) out[i] = (v[i] - bn3[0]) * bn3[1] + be3[0];
}

extern "C" void kernel_launch(void* const* d_in, const int* in_sizes, int n_in,
                              void* d_out, int out_size, void* d_ws, size_t ws_size,
                              hipStream_t stream) {
    (void)in_sizes; (void)n_in; (void)out_size; (void)ws_size;
    const float* tgt = (const float*)d_in[0];
    const float* mem = (const float*)d_in[1];
    const float* W1  = (const float*)d_in[2];
    const float* b1  = (const float*)d_in[3];
    const float* se  = (const float*)d_in[4];
    const float* W2  = (const float*)d_in[5];
    const float* b2  = (const float*)d_in[6];
    const float* W3  = (const float*)d_in[7];
    const float* b3  = (const float*)d_in[8];
    const float* g1  = (const float*)d_in[9];
    const float* be1 = (const float*)d_in[10];
    const float* g2  = (const float*)d_in[11];
    const float* be2 = (const float*)d_in[12];
    const float* g3  = (const float*)d_in[13];
    const float* be3 = (const float*)d_in[14];
    const int*  flag = (const int*)d_in[15];
    (void)b2;  // cancels analytically through BN2's mean-subtract
    float* out = (float*)d_out;

    char* ws = (char*)d_ws;
    size_t off = 0;
    auto alloc = [&](size_t bytes) -> void* {
        void* p = ws + off;
        off = (off + bytes + 255) & ~(size_t)255;
        return p;
    };
    float* sig   = (float*)alloc((size_t)SSZ * SSZ * 4);
    __hip_bfloat16* Xb  = (__hip_bfloat16*)alloc((size_t)NX * D * 2);   // 21 MB
    __hip_bfloat16* W1b = (__hip_bfloat16*)alloc((size_t)D * D * 2);    // 0.5 MB
    __hip_bfloat16* W2b = (__hip_bfloat16*)alloc((size_t)FF * 64 * 2);  // 0.25 MB
    __hip_bfloat16* QKb = (__hip_bfloat16*)alloc((size_t)NX * D * 2);   // 21 MB
    float* xbuf  = (float*)alloc((size_t)ROWSX * 64 * 4);               // 8 MB
    float* z     = (float*)alloc((size_t)ROWSX * 4);
    float* v     = (float*)alloc((size_t)PAIRS * 4);
    float* alpha = (float*)alloc((size_t)FF * 4);
    float* beta  = (float*)alloc((size_t)FF * 4);
    float* xbarn = (float*)alloc(64 * 4);
    float* covn  = (float*)alloc(64 * 64 * 4);
    float* bn1   = (float*)alloc(16);
    float* bn3   = (float*)alloc(16);
    size_t statsStart = off;
    double* S1d   = (double*)alloc(64 * 8);
    double* S2d   = (double*)alloc(64 * 64 * 8);
    double* sums3 = (double*)alloc(2 * 8);
    size_t statsEnd = off;

    hipMemsetAsync(ws + statsStart, 0, statsEnd - statsStart, stream);

    k_sig<<<16, 256, 0, stream>>>(se, flag, sig);
    constexpr int CVT4 = (NX * D + D * D + FF * 64) / 4;
    k_cvt<<<(CVT4 + 255) / 256, 256, 0, stream>>>(tgt, mem, W1, W2, Xb, W1b, W2b);
    k_gemm1_mfma<<<(NX / 128) * (D / 128), 256, 0, stream>>>(Xb, W1b, b1, flag, QKb);
    // flattened score GEMM: (NK*SSZ/128) x (NQ*SSZ/128) = 128 x 32 = 4096 blocks
    k_score_mfma<<<(NK * SSZ / 128) * (NQ * SSZ / 128), 256, 0, stream>>>(QKb, sig, xbuf);
    k_stats1<<<128, 256, 0, stream>>>(xbuf, S1d, S2d);
    k_fin1<<<1, 256, 0, stream>>>(S1d, S2d, g1, be1, bn1, xbarn, covn);
    k_bn2<<<FF, 64, 0, stream>>>(covn, xbarn, W2b, g2, be2, alpha, beta);
    k_mlp_mfma<<<ROWSX / 128, 256, 0, stream>>>(xbuf, bn1, be1, W2b, alpha, beta, W3, b3, z);
    k_pair<<<PAIRS / 256, 256, 0, stream>>>(z, v, sums3);
    k_fin3<<<1, 1, 0, stream>>>(sums3, g3, bn3);
    k_out<<<PAIRS / 256, 256, 0, stream>>>(v, bn3, be3, out);
}